// Round 2
// baseline (2563.004 us; speedup 1.0000x reference)
//
#include <hip/hip_runtime.h>
#include <hip/hip_bf16.h>

using bf16 = __hip_bfloat16;
static __device__ __forceinline__ float b2f(bf16 x) { return __bfloat162float(x); }

// ---------------- dtype auto-detection (deterministic, same every call) ------
// flags[0]=1 -> float inputs are fp32 (else bf16). flags[1]=1 -> edges int64.
__global__ void det_kernel(const unsigned short* __restrict__ xh,
                           const int* __restrict__ ei, int* __restrict__ flags) {
    __shared__ int s_exp, s_nz;
    if (threadIdx.x == 0) { s_exp = 0; s_nz = 0; }
    __syncthreads();
    // bf16 N(0,1) halfwords have exponent field ~[113,130]; fp32 low-mantissa
    // halves are uniform random -> ~84% land outside [100,140].
    if (threadIdx.x < 256) {
        unsigned short h = xh[threadIdx.x];
        int ef = (h >> 7) & 0xFF;
        if (ef < 100 || ef > 140) atomicAdd(&s_exp, 1);
    }
    // int64 indices < 2^31: every odd 32-bit word is 0. int32 real indices: not.
    for (int i = 1 + 2 * threadIdx.x; i < 4096; i += 2 * blockDim.x)
        if (ei[i] != 0) atomicAdd(&s_nz, 1);
    __syncthreads();
    if (threadIdx.x == 0) {
        flags[0] = (s_exp > 16) ? 1 : 0;
        flags[1] = (s_nz == 0) ? 1 : 0;
    }
}

// ---------------- canonicalizers --------------------------------------------
__global__ void canon_w(const void* __restrict__ src, const int* __restrict__ flags,
                        float* __restrict__ dst, int n) {
    int i = blockIdx.x * blockDim.x + threadIdx.x;
    if (i >= n) return;
    dst[i] = flags[0] ? ((const float*)src)[i] : b2f(((const bf16*)src)[i]);
}

__global__ void canon_x(const void* __restrict__ src, const int* __restrict__ flags,
                        bf16* __restrict__ dst, int n) {
    int i = blockIdx.x * blockDim.x + threadIdx.x;
    if (i >= n) return;
    dst[i] = flags[0] ? __float2bfloat16(((const float*)src)[i]) : ((const bf16*)src)[i];
}

__global__ void canon_edges(const int* __restrict__ ei, const int* __restrict__ flags,
                            int* __restrict__ srcd, int* __restrict__ dstd, int E) {
    int e = blockIdx.x * blockDim.x + threadIdx.x;
    if (e >= E) return;
    if (flags[1]) { srcd[e] = ei[2 * e]; dstd[e] = ei[2 * E + 2 * e]; }
    else          { srcd[e] = ei[e];     dstd[e] = ei[E + e]; }
}

// ---------------- degree ----------------------------------------------------
__global__ void deg_kernel(const int* __restrict__ dstv, float* __restrict__ deg, int E) {
    int e = blockIdx.x * blockDim.x + threadIdx.x;
    if (e < E) atomicAdd(&deg[dstv[e]], 1.0f);
}
__global__ void dinv_kernel(float* __restrict__ dinv, int N) {
    int i = blockIdx.x * blockDim.x + threadIdx.x;
    if (i < N) dinv[i] = rsqrtf(dinv[i] + 1.0f);
}

// ---------------- GEMM: C[N,F](bf16) = A[N,K](bf16) @ W[k*Wld+f](fp32) + bias
// 8 rows/block in LDS(fp32); W column-sliced via Wld for chunked layers.
template <int K>
__global__ void gemm_kernel(const bf16* __restrict__ A, const float* __restrict__ W,
                            int Wld, const float* __restrict__ bias,
                            bf16* __restrict__ C, int F, int N) {
    __shared__ float a_lds[8 * K];
    const int row0 = blockIdx.x * 8;            // N % 8 == 0
    const size_t base = (size_t)row0 * K;
    for (int i = threadIdx.x; i < 8 * K; i += blockDim.x) a_lds[i] = b2f(A[base + i]);
    __syncthreads();
    for (int f = threadIdx.x; f < F; f += blockDim.x) {
        float acc[8];
#pragma unroll
        for (int r = 0; r < 8; ++r) acc[r] = 0.0f;
#pragma unroll 4
        for (int k = 0; k < K; ++k) {
            float w = W[(size_t)k * Wld + f];
#pragma unroll
            for (int r = 0; r < 8; ++r) acc[r] += a_lds[r * K + k] * w;
        }
        float bv = bias ? bias[f] : 0.0f;
#pragma unroll
        for (int r = 0; r < 8; ++r)
            C[(size_t)(row0 + r) * F + f] = __float2bfloat16(acc[r] + bv);
    }
}

// Final GEMM: writes d_out in detected dtype.
template <int K>
__global__ void gemm_out_kernel(const bf16* __restrict__ A, const float* __restrict__ W,
                                const float* __restrict__ bias, void* __restrict__ out,
                                const int* __restrict__ flags, int F, int N) {
    __shared__ float a_lds[8 * K];
    const int row0 = blockIdx.x * 8;
    const size_t base = (size_t)row0 * K;
    for (int i = threadIdx.x; i < 8 * K; i += blockDim.x) a_lds[i] = b2f(A[base + i]);
    __syncthreads();
    const int m32 = flags[0];
    for (int f = threadIdx.x; f < F; f += blockDim.x) {
        float acc[8];
#pragma unroll
        for (int r = 0; r < 8; ++r) acc[r] = 0.0f;
#pragma unroll 4
        for (int k = 0; k < K; ++k) {
            float w = W[(size_t)k * F + f];
#pragma unroll
            for (int r = 0; r < 8; ++r) acc[r] += a_lds[r * K + k] * w;
        }
        float bv = bias[f];
#pragma unroll
        for (int r = 0; r < 8; ++r) {
            float v = acc[r] + bv;
            size_t o = (size_t)(row0 + r) * F + f;
            if (m32) ((float*)out)[o] = v;
            else     ((bf16*)out)[o] = __float2bfloat16(v);
        }
    }
}

// ---------------- scatter-aggregate (fp32 atomics) --------------------------
template <int F>
__global__ void agg_kernel(const bf16* __restrict__ H, const int* __restrict__ srcv,
                           const int* __restrict__ dstv, const float* __restrict__ dinv,
                           float* __restrict__ AGG, int E) {
    size_t gid = blockIdx.x * (size_t)blockDim.x + threadIdx.x;
    int e = (int)(gid / F);
    if (e >= E) return;
    int f = (int)(gid % F);
    int s = srcv[e], d = dstv[e];
    float c = dinv[s] * dinv[d];
    atomicAdd(&AGG[(size_t)d * F + f], b2f(H[(size_t)s * F + f]) * c);
}

// out[i*outStride + colOff + f] = act(AGG[i*F+f] + H[i*F+f]*dinv[i]^2 + bias[f])
__global__ void combine_kernel(const float* __restrict__ AGG, const bf16* __restrict__ H,
                               const float* __restrict__ dinv, const float* __restrict__ bias,
                               bf16* __restrict__ out, int fShift, int outStride, int colOff,
                               int relu, int total) {
    int gid = blockIdx.x * blockDim.x + threadIdx.x;
    if (gid >= total) return;
    int i = gid >> fShift;
    int f = gid & ((1 << fShift) - 1);
    float di = dinv[i];
    float v = AGG[gid] + b2f(H[gid]) * di * di + bias[f];
    if (relu) v = fmaxf(v, 0.0f);
    out[(size_t)i * outStride + colOff + f] = __float2bfloat16(v);
}

// ---------------- link predictor --------------------------------------------
__global__ void link_kernel(const bf16* __restrict__ Z, const int* __restrict__ srcv,
                            const int* __restrict__ dstv, const float* __restrict__ lw,
                            const float* __restrict__ lb, void* __restrict__ out,
                            const int* __restrict__ flags, size_t outOff, int E) {
    size_t gtid = blockIdx.x * (size_t)blockDim.x + threadIdx.x;
    int e = (int)(gtid >> 6);
    int lane = (int)(gtid & 63);
    if (e >= E) return;
    int s = srcv[e], d = dstv[e];
    float v = b2f(Z[(size_t)s * 64 + lane]) * lw[lane]
            + b2f(Z[(size_t)d * 64 + lane]) * lw[64 + lane];
#pragma unroll
    for (int off = 32; off > 0; off >>= 1) v += __shfl_down(v, off);
    if (lane == 0) {
        float sv = 1.0f / (1.0f + expf(-(v + lb[0])));
        if (flags[0]) ((float*)out)[outOff + e] = sv;
        else          ((bf16*)out)[outOff + e] = __float2bfloat16(sv);
    }
}

// ---------------- launch ----------------------------------------------------
extern "C" void kernel_launch(void* const* d_in, const int* in_sizes, int n_in,
                              void* d_out, int out_size, void* d_ws, size_t ws_size,
                              hipStream_t stream) {
    const int N = in_sizes[0] / 128;   // 50000 (divisible by 8)
    const int E = in_sizes[1] / 2;     // 800000

    // ws layout (256B-aligned slices), total ~78 MB
    char* base = (char*)d_ws;
    size_t off = 0;
    auto alloc = [&](size_t bytes) { char* p = base + off; off = (off + bytes + 255) & ~(size_t)255; return p; };
    int*   flags = (int*)  alloc(256);
    float* dinv  = (float*)alloc((size_t)N * 4);
    float* Wc    = (float*)alloc((size_t)210689 * 4);
    int*   srcd  = (int*)  alloc((size_t)E * 4);
    int*   dstd  = (int*)  alloc((size_t)E * 4);
    float* AGG   = (float*)alloc((size_t)N * 128 * 4);
    bf16*  P0    = (bf16*) alloc((size_t)N * 256 * 2);
    bf16*  P1    = (bf16*) alloc((size_t)N * 128 * 2);
    bf16*  z     = (bf16*) alloc((size_t)N * 64 * 2);

    // canonical fp32 weight offsets
    const int W_EW1 = 0, W_EB1 = 16384, W_EW2 = 16512, W_EB2 = 24704,
              W_EFW = 24768, W_EFB = 28864, W_DW1 = 28928, W_DB1 = 45312,
              W_DW2 = 45568, W_DB2 = 78336, W_DFW = 78464, W_DFB = 209536,
              W_LW = 210560, W_LB = 210688;

    det_kernel<<<1, 256, 0, stream>>>((const unsigned short*)d_in[0], (const int*)d_in[1], flags);
    canon_edges<<<(E + 255) / 256, 256, 0, stream>>>((const int*)d_in[1], flags, srcd, dstd, E);

    hipMemsetAsync(dinv, 0, (size_t)N * 4, stream);
    deg_kernel<<<(E + 255) / 256, 256, 0, stream>>>(dstd, dinv, E);
    dinv_kernel<<<(N + 255) / 256, 256, 0, stream>>>(dinv, N);

    {   // weights -> canonical fp32
        const int idx[14] = {2, 3, 4, 5, 6, 7, 8, 9, 10, 11, 12, 13, 14, 15};
        const int woff[14] = {W_EW1, W_EB1, W_EW2, W_EB2, W_EFW, W_EFB, W_DW1,
                              W_DB1, W_DW2, W_DB2, W_DFW, W_DFB, W_LW, W_LB};
        for (int j = 0; j < 14; ++j) {
            int n = in_sizes[idx[j]];
            canon_w<<<(n + 255) / 256, 256, 0, stream>>>(d_in[idx[j]], flags, Wc + woff[j], n);
        }
    }
    canon_x<<<(N * 128 + 255) / 256, 256, 0, stream>>>(d_in[0], flags, P0, N * 128);

    const int gN8 = N / 8;

    // Encoder GCN1: 128 -> 128, ReLU.  P0(x) -> P1(h) -> P0
    gemm_kernel<128><<<gN8, 256, 0, stream>>>(P0, Wc + W_EW1, 128, nullptr, P1, 128, N);
    hipMemsetAsync(AGG, 0, (size_t)N * 128 * 4, stream);
    agg_kernel<128><<<((size_t)E * 128 + 255) / 256, 256, 0, stream>>>(P1, srcd, dstd, dinv, AGG, E);
    combine_kernel<<<(N * 128 + 255) / 256, 256, 0, stream>>>(AGG, P1, dinv, Wc + W_EB1, P0, 7, 128, 0, 1, N * 128);

    // Encoder GCN2: 128 -> 64.  P0 -> P1 -> P0
    gemm_kernel<128><<<gN8, 256, 0, stream>>>(P0, Wc + W_EW2, 64, nullptr, P1, 64, N);
    hipMemsetAsync(AGG, 0, (size_t)N * 64 * 4, stream);
    agg_kernel<64><<<((size_t)E * 64 + 255) / 256, 256, 0, stream>>>(P1, srcd, dstd, dinv, AGG, E);
    combine_kernel<<<(N * 64 + 255) / 256, 256, 0, stream>>>(AGG, P1, dinv, Wc + W_EB2, P0, 6, 64, 0, 0, N * 64);

    // Latent: z = P0 @ efw + efb  (64 -> 64)
    gemm_kernel<64><<<gN8, 256, 0, stream>>>(P0, Wc + W_EFW, 64, Wc + W_EFB, z, 64, N);

    // Decoder GCN1: 64 -> 256, ReLU, two 128-feature chunks: z -> P1 -> P0[:, c*128:]
    for (int c = 0; c < 2; ++c) {
        gemm_kernel<64><<<gN8, 256, 0, stream>>>(z, Wc + W_DW1 + c * 128, 256, nullptr, P1, 128, N);
        hipMemsetAsync(AGG, 0, (size_t)N * 128 * 4, stream);
        agg_kernel<128><<<((size_t)E * 128 + 255) / 256, 256, 0, stream>>>(P1, srcd, dstd, dinv, AGG, E);
        combine_kernel<<<(N * 128 + 255) / 256, 256, 0, stream>>>(AGG, P1, dinv, Wc + W_DB1 + c * 128, P0, 7, 256, c * 128, 1, N * 128);
    }

    // Decoder GCN2: 256 -> 128.  P0 -> P1 -> P0 (compact)
    gemm_kernel<256><<<gN8, 256, 0, stream>>>(P0, Wc + W_DW2, 128, nullptr, P1, 128, N);
    hipMemsetAsync(AGG, 0, (size_t)N * 128 * 4, stream);
    agg_kernel<128><<<((size_t)E * 128 + 255) / 256, 256, 0, stream>>>(P1, srcd, dstd, dinv, AGG, E);
    combine_kernel<<<(N * 128 + 255) / 256, 256, 0, stream>>>(AGG, P1, dinv, Wc + W_DB2, P0, 7, 128, 0, 0, N * 128);

    // x_hat: P0 @ dfw + dfb (128 -> 1024) into d_out (dtype per flags)
    gemm_out_kernel<128><<<gN8, 256, 0, stream>>>(P0, Wc + W_DFW, Wc + W_DFB, d_out, flags, 1024, N);

    // edge_probs
    link_kernel<<<((size_t)E * 64 + 255) / 256, 256, 0, stream>>>(z, srcd, dstd, Wc + W_LW, Wc + W_LB,
                                                                  d_out, flags, (size_t)N * 1024, E);
}

// Round 3
// 1238.630 us; speedup vs baseline: 2.0692x; 2.0692x over previous
//
#include <hip/hip_runtime.h>
#include <hip/hip_bf16.h>

using bf16 = __hip_bfloat16;
static __device__ __forceinline__ float b2f(bf16 x) { return __bfloat162float(x); }

static __device__ __forceinline__ unsigned int packbf2(float a, float b) {
    bf16 x = __float2bfloat16(a), y = __float2bfloat16(b);
    unsigned short ux = *(unsigned short*)&x, uy = *(unsigned short*)&y;
    return (unsigned int)ux | ((unsigned int)uy << 16);
}

// ---------------- dtype auto-detection (deterministic) -----------------------
// flags[0]=1 -> float inputs are fp32 (else bf16). flags[1]=1 -> edges int64.
__global__ void det_kernel(const unsigned short* __restrict__ xh,
                           const int* __restrict__ ei, int* __restrict__ flags) {
    __shared__ int s_exp, s_nz;
    if (threadIdx.x == 0) { s_exp = 0; s_nz = 0; }
    __syncthreads();
    if (threadIdx.x < 256) {
        unsigned short h = xh[threadIdx.x];
        int ef = (h >> 7) & 0xFF;
        if (ef < 100 || ef > 140) atomicAdd(&s_exp, 1);
    }
    for (int i = 1 + 2 * threadIdx.x; i < 4096; i += 2 * blockDim.x)
        if (ei[i] != 0) atomicAdd(&s_nz, 1);
    __syncthreads();
    if (threadIdx.x == 0) {
        flags[0] = (s_exp > 16) ? 1 : 0;
        flags[1] = (s_nz == 0) ? 1 : 0;
    }
}

// ---------------- canonicalizers --------------------------------------------
__global__ void canon_w(const void* __restrict__ src, const int* __restrict__ flags,
                        float* __restrict__ dst, int n) {
    int i = blockIdx.x * blockDim.x + threadIdx.x;
    if (i >= n) return;
    dst[i] = flags[0] ? ((const float*)src)[i] : b2f(((const bf16*)src)[i]);
}

__global__ void canon_x(const void* __restrict__ src, const int* __restrict__ flags,
                        bf16* __restrict__ dst, int n) {
    int i = blockIdx.x * blockDim.x + threadIdx.x;
    if (i >= n) return;
    dst[i] = flags[0] ? __float2bfloat16(((const float*)src)[i]) : ((const bf16*)src)[i];
}

__global__ void canon_edges(const int* __restrict__ ei, const int* __restrict__ flags,
                            int* __restrict__ srcd, int* __restrict__ dstd, int E) {
    int e = blockIdx.x * blockDim.x + threadIdx.x;
    if (e >= E) return;
    if (flags[1]) { srcd[e] = ei[2 * e]; dstd[e] = ei[2 * E + 2 * e]; }
    else          { srcd[e] = ei[e];     dstd[e] = ei[E + e]; }
}

// ---------------- CSR build -------------------------------------------------
__global__ void hist_kernel(const int* __restrict__ dstv, int* __restrict__ counts, int E) {
    int e = blockIdx.x * blockDim.x + threadIdx.x;
    if (e < E) atomicAdd(&counts[dstv[e]], 1);
}

// single-block exclusive scan over counts[0..N) -> rowPtr, cursor; also dinv.
__global__ void scan_kernel(const int* __restrict__ counts, int* __restrict__ rowPtr,
                            int* __restrict__ cursor, float* __restrict__ dinv, int N) {
    __shared__ int sums[1024];
    const int tid = threadIdx.x;
    const int chunk = (N + 1023) / 1024;
    int beg = tid * chunk, end = beg + chunk;
    if (beg > N) beg = N;
    if (end > N) end = N;
    int s = 0;
    for (int i = beg; i < end; ++i) s += counts[i];
    sums[tid] = s;
    __syncthreads();
    for (int off = 1; off < 1024; off <<= 1) {
        int v = (tid >= off) ? sums[tid - off] : 0;
        __syncthreads();
        sums[tid] += v;
        __syncthreads();
    }
    int run = (tid > 0) ? sums[tid - 1] : 0;
    for (int i = beg; i < end; ++i) {
        rowPtr[i] = run; cursor[i] = run;
        dinv[i] = rsqrtf((float)counts[i] + 1.0f);
        run += counts[i];
    }
    if (tid == 1023) rowPtr[N] = run;
}

__global__ void scatter_kernel(const int* __restrict__ srcv, const int* __restrict__ dstv,
                               int* __restrict__ cursor, int* __restrict__ sortedSrc, int E) {
    int e = blockIdx.x * blockDim.x + threadIdx.x;
    if (e >= E) return;
    int p = atomicAdd(&cursor[dstv[e]], 1);
    sortedSrc[p] = srcv[e];
}

// ---------------- GEMM: C[N,F](bf16) = A[N,K](bf16) @ W(fp32) [+bias][*dinv] -
template <int K>
__global__ void gemm_kernel(const bf16* __restrict__ A, const float* __restrict__ W,
                            const float* __restrict__ bias, const float* __restrict__ dinv,
                            bf16* __restrict__ C, int F, int N) {
    __shared__ float a_lds[8 * K];
    const int row0 = blockIdx.x * 8;           // N % 8 == 0
    const size_t base = (size_t)row0 * K;
    for (int i = threadIdx.x; i < 8 * K; i += blockDim.x) a_lds[i] = b2f(A[base + i]);
    __syncthreads();
    float dv[8];
#pragma unroll
    for (int r = 0; r < 8; ++r) dv[r] = dinv ? dinv[row0 + r] : 1.0f;
    for (int f = threadIdx.x; f < F; f += blockDim.x) {
        float acc[8];
#pragma unroll
        for (int r = 0; r < 8; ++r) acc[r] = 0.0f;
#pragma unroll 4
        for (int k = 0; k < K; ++k) {
            float w = W[(size_t)k * F + f];
#pragma unroll
            for (int r = 0; r < 8; ++r) acc[r] += a_lds[r * K + k] * w;
        }
        float bv = bias ? bias[f] : 0.0f;
#pragma unroll
        for (int r = 0; r < 8; ++r)
            C[(size_t)(row0 + r) * F + f] = __float2bfloat16(acc[r] * dv[r] + bv);
    }
}

// Final GEMM: writes d_out in detected dtype.
template <int K>
__global__ void gemm_out_kernel(const bf16* __restrict__ A, const float* __restrict__ W,
                                const float* __restrict__ bias, void* __restrict__ out,
                                const int* __restrict__ flags, int F, int N) {
    __shared__ float a_lds[8 * K];
    const int row0 = blockIdx.x * 8;
    const size_t base = (size_t)row0 * K;
    for (int i = threadIdx.x; i < 8 * K; i += blockDim.x) a_lds[i] = b2f(A[base + i]);
    __syncthreads();
    const int m32 = flags[0];
    for (int f = threadIdx.x; f < F; f += blockDim.x) {
        float acc[8];
#pragma unroll
        for (int r = 0; r < 8; ++r) acc[r] = 0.0f;
#pragma unroll 4
        for (int k = 0; k < K; ++k) {
            float w = W[(size_t)k * F + f];
#pragma unroll
            for (int r = 0; r < 8; ++r) acc[r] += a_lds[r * K + k] * w;
        }
        float bv = bias[f];
#pragma unroll
        for (int r = 0; r < 8; ++r) {
            float v = acc[r] + bv;
            size_t o = (size_t)(row0 + r) * F + f;
            if (m32) ((float*)out)[o] = v;
            else     ((bf16*)out)[o] = __float2bfloat16(v);
        }
    }
}

// ---------------- fused gather-aggregate + self-loop + bias + act -----------
// out[d] = act( dinv[d] * (sum_{s in in(d)} H'[s] + H'[d]) + bias )
template <int F>
static __device__ __forceinline__ void acc_row(const bf16* __restrict__ Hs, int row, int lane,
                                               float* acc) {
    if constexpr (F == 64) {
        unsigned short u = ((const unsigned short*)Hs)[(size_t)row * 64 + lane];
        union { unsigned int i; float f; } c; c.i = (unsigned int)u << 16;
        acc[0] += c.f;
    } else if constexpr (F == 128) {
        unsigned int u = ((const unsigned int*)(Hs + (size_t)row * 128))[lane];
        union { unsigned int i; float f; } lo, hi;
        lo.i = u << 16; hi.i = u & 0xffff0000u;
        acc[0] += lo.f; acc[1] += hi.f;
    } else {
        uint2 u = ((const uint2*)(Hs + (size_t)row * 256))[lane];
        union { unsigned int i; float f; } a, b, c, d;
        a.i = u.x << 16; b.i = u.x & 0xffff0000u;
        c.i = u.y << 16; d.i = u.y & 0xffff0000u;
        acc[0] += a.f; acc[1] += b.f; acc[2] += c.f; acc[3] += d.f;
    }
}

template <int F>
__global__ void gather_kernel(const bf16* __restrict__ Hs, const int* __restrict__ rowPtr,
                              const int* __restrict__ sortedSrc, const float* __restrict__ dinv,
                              const float* __restrict__ bias, bf16* __restrict__ out,
                              int relu, int N) {
    constexpr int WPL = F / 64;                    // bf16 per lane
    int node = blockIdx.x * (blockDim.x >> 6) + (threadIdx.x >> 6);
    int lane = threadIdx.x & 63;
    if (node >= N) return;
    float acc[WPL];
#pragma unroll
    for (int w = 0; w < WPL; ++w) acc[w] = 0.0f;
    acc_row<F>(Hs, node, lane, acc);               // self-loop term
    const int beg = rowPtr[node], end = rowPtr[node + 1];
    for (int b = beg; b < end; b += 64) {
        int n = end - b; if (n > 64) n = 64;
        int myS = (lane < n) ? sortedSrc[b + lane] : 0;
        int j = 0;
        for (; j + 1 < n; j += 2) {               // 2 gathers in flight
            int s0 = __shfl(myS, j), s1 = __shfl(myS, j + 1);
            acc_row<F>(Hs, s0, lane, acc);
            acc_row<F>(Hs, s1, lane, acc);
        }
        if (j < n) acc_row<F>(Hs, __shfl(myS, j), lane, acc);
    }
    const float di = dinv[node];
    if constexpr (F == 64) {
        float v = acc[0] * di + bias[lane];
        if (relu) v = fmaxf(v, 0.0f);
        bf16 o = __float2bfloat16(v);
        ((unsigned short*)out)[(size_t)node * 64 + lane] = *(unsigned short*)&o;
    } else if constexpr (F == 128) {
        float v0 = acc[0] * di + bias[2 * lane];
        float v1 = acc[1] * di + bias[2 * lane + 1];
        if (relu) { v0 = fmaxf(v0, 0.0f); v1 = fmaxf(v1, 0.0f); }
        ((unsigned int*)(out + (size_t)node * 128))[lane] = packbf2(v0, v1);
    } else {
        float v0 = acc[0] * di + bias[4 * lane];
        float v1 = acc[1] * di + bias[4 * lane + 1];
        float v2 = acc[2] * di + bias[4 * lane + 2];
        float v3 = acc[3] * di + bias[4 * lane + 3];
        if (relu) { v0 = fmaxf(v0, 0.0f); v1 = fmaxf(v1, 0.0f);
                    v2 = fmaxf(v2, 0.0f); v3 = fmaxf(v3, 0.0f); }
        uint2 p; p.x = packbf2(v0, v1); p.y = packbf2(v2, v3);
        ((uint2*)(out + (size_t)node * 256))[lane] = p;
    }
}

// ---------------- link predictor --------------------------------------------
__global__ void link_kernel(const bf16* __restrict__ Z, const int* __restrict__ srcv,
                            const int* __restrict__ dstv, const float* __restrict__ lw,
                            const float* __restrict__ lb, void* __restrict__ out,
                            const int* __restrict__ flags, size_t outOff, int E) {
    size_t gtid = blockIdx.x * (size_t)blockDim.x + threadIdx.x;
    int e = (int)(gtid >> 6);
    int lane = (int)(gtid & 63);
    if (e >= E) return;
    int s = srcv[e], d = dstv[e];
    float v = b2f(Z[(size_t)s * 64 + lane]) * lw[lane]
            + b2f(Z[(size_t)d * 64 + lane]) * lw[64 + lane];
#pragma unroll
    for (int off = 32; off > 0; off >>= 1) v += __shfl_down(v, off);
    if (lane == 0) {
        float sv = 1.0f / (1.0f + expf(-(v + lb[0])));
        if (flags[0]) ((float*)out)[outOff + e] = sv;
        else          ((bf16*)out)[outOff + e] = __float2bfloat16(sv);
    }
}

// ---------------- launch ----------------------------------------------------
extern "C" void kernel_launch(void* const* d_in, const int* in_sizes, int n_in,
                              void* d_out, int out_size, void* d_ws, size_t ws_size,
                              hipStream_t stream) {
    const int N = in_sizes[0] / 128;   // 50000 (divisible by 8)
    const int E = in_sizes[1] / 2;     // 800000

    char* base = (char*)d_ws;
    size_t off = 0;
    auto alloc = [&](size_t bytes) { char* p = base + off; off = (off + bytes + 255) & ~(size_t)255; return p; };
    int*   flags  = (int*)  alloc(256);
    float* dinv   = (float*)alloc((size_t)N * 4);
    float* Wc     = (float*)alloc((size_t)210689 * 4);
    int*   counts = (int*)  alloc((size_t)N * 4);
    int*   rowPtr = (int*)  alloc(((size_t)N + 1) * 4);
    int*   cursor = (int*)  alloc((size_t)N * 4);
    int*   sortedSrc = (int*)alloc((size_t)E * 4);
    int*   srcd   = (int*)  alloc((size_t)E * 4);
    int*   dstd   = (int*)  alloc((size_t)E * 4);
    bf16*  Hs     = (bf16*) alloc((size_t)N * 256 * 2);  // scaled GEMM out H'
    bf16*  P0     = (bf16*) alloc((size_t)N * 256 * 2);  // layer output
    bf16*  z      = (bf16*) alloc((size_t)N * 64 * 2);

    const int W_EW1 = 0, W_EB1 = 16384, W_EW2 = 16512, W_EB2 = 24704,
              W_EFW = 24768, W_EFB = 28864, W_DW1 = 28928, W_DB1 = 45312,
              W_DW2 = 45568, W_DB2 = 78336, W_DFW = 78464, W_DFB = 209536,
              W_LW = 210560, W_LB = 210688;

    det_kernel<<<1, 256, 0, stream>>>((const unsigned short*)d_in[0], (const int*)d_in[1], flags);
    canon_edges<<<(E + 255) / 256, 256, 0, stream>>>((const int*)d_in[1], flags, srcd, dstd, E);

    // CSR + dinv
    hipMemsetAsync(counts, 0, (size_t)N * 4, stream);
    hist_kernel<<<(E + 255) / 256, 256, 0, stream>>>(dstd, counts, E);
    scan_kernel<<<1, 1024, 0, stream>>>(counts, rowPtr, cursor, dinv, N);
    scatter_kernel<<<(E + 255) / 256, 256, 0, stream>>>(srcd, dstd, cursor, sortedSrc, E);

    {   // weights -> canonical fp32
        const int idx[14] = {2, 3, 4, 5, 6, 7, 8, 9, 10, 11, 12, 13, 14, 15};
        const int woff[14] = {W_EW1, W_EB1, W_EW2, W_EB2, W_EFW, W_EFB, W_DW1,
                              W_DB1, W_DW2, W_DB2, W_DFW, W_DFB, W_LW, W_LB};
        for (int j = 0; j < 14; ++j) {
            int n = in_sizes[idx[j]];
            canon_w<<<(n + 255) / 256, 256, 0, stream>>>(d_in[idx[j]], flags, Wc + woff[j], n);
        }
    }
    canon_x<<<(N * 128 + 255) / 256, 256, 0, stream>>>(d_in[0], flags, P0, N * 128);

    const int gN8 = N / 8;
    const int gG = (N + 3) / 4;        // gather: 4 nodes (waves) per 256-block

    // Encoder GCN1: 128 -> 128, ReLU
    gemm_kernel<128><<<gN8, 128, 0, stream>>>(P0, Wc + W_EW1, nullptr, dinv, Hs, 128, N);
    gather_kernel<128><<<gG, 256, 0, stream>>>(Hs, rowPtr, sortedSrc, dinv, Wc + W_EB1, P0, 1, N);

    // Encoder GCN2: 128 -> 64
    gemm_kernel<128><<<gN8, 64, 0, stream>>>(P0, Wc + W_EW2, nullptr, dinv, Hs, 64, N);
    gather_kernel<64><<<gG, 256, 0, stream>>>(Hs, rowPtr, sortedSrc, dinv, Wc + W_EB2, P0, 0, N);

    // Latent fc: z = P0 @ efw + efb
    gemm_kernel<64><<<gN8, 64, 0, stream>>>(P0, Wc + W_EFW, Wc + W_EFB, nullptr, z, 64, N);

    // Decoder GCN1: 64 -> 256, ReLU
    gemm_kernel<64><<<gN8, 256, 0, stream>>>(z, Wc + W_DW1, nullptr, dinv, Hs, 256, N);
    gather_kernel<256><<<gG, 256, 0, stream>>>(Hs, rowPtr, sortedSrc, dinv, Wc + W_DB1, P0, 1, N);

    // Decoder GCN2: 256 -> 128
    gemm_kernel<256><<<gN8, 128, 0, stream>>>(P0, Wc + W_DW2, nullptr, dinv, Hs, 128, N);
    gather_kernel<128><<<gG, 256, 0, stream>>>(Hs, rowPtr, sortedSrc, dinv, Wc + W_DB2, P0, 0, N);

    // x_hat = P0 @ dfw + dfb (128 -> 1024) into d_out
    gemm_out_kernel<128><<<gN8, 256, 0, stream>>>(P0, Wc + W_DFW, Wc + W_DFB, d_out, flags, 1024, N);

    // edge_probs
    link_kernel<<<((size_t)E * 64 + 255) / 256, 256, 0, stream>>>(z, srcd, dstd, Wc + W_LW, Wc + W_LB,
                                                                  d_out, flags, (size_t)N * 1024, E);
}